// Round 7
// baseline (451.323 us; speedup 1.0000x reference)
//
#include <hip/hip_runtime.h>
#include <hip/hip_bf16.h>

// ECE loss, train path:
//   conf[r]  = max(softmax(logits[r,:])) = 1 / sum(exp(l - max))
//   pred[r]  = argmax(logits[r,:])   (first index on ties, matches jnp.argmax)
//   bin      = clip(ceil(conf*10)-1, 0, 9)
//   ece      = sum_b |conf_sum/cnt - corr_sum/cnt| * cnt/N   over non-empty bins
//
// R6 post-mortem: 16-lane-group + shuffle-butterfly version ran 177.8 us at
// 9.3% HBM, 19% VALU, 0 bank conflicts -> latency/DS-pipe bound on ~12
// ds_bpermute round-trips per row, NOT memory bound. FETCH_SIZE=132MB (L3
// holds half the logits), so memory floor is ~25-30 us.
// This round: thread-per-row. Zero shuffles; per-lane 16x float4 row read
// (per-lane sequential, L1 absorbs the stride-256B transpose); in-register
// argmax with first-index tie-break; 3 LDS atomics/row (same per-row atomic
// work as before, 1/16th the instructions).

#define N_BINS 10
#define C 64

// ws layout: [0..9] cnt, [10..19] conf_sum, [20..29] corr_sum (doubles), then counter.
#define WS_COUNTER_OFF 30  // in doubles

__global__ void ece_init_ws(double* ws) {
    int t = threadIdx.x;
    if (t < 3 * N_BINS) ws[t] = 0.0;
    if (t == 0) *(unsigned int*)(ws + WS_COUNTER_OFF) = 0u;
}

__global__ __launch_bounds__(256) void ece_main(const float* __restrict__ logits,
                                                const int* __restrict__ labels,
                                                double* __restrict__ gbins,
                                                float* __restrict__ out,
                                                int N) {
    __shared__ float s_cnt[N_BINS];
    __shared__ float s_conf[N_BINS];
    __shared__ float s_corr[N_BINS];
    __shared__ int s_last;
    const int tid = threadIdx.x;
    if (tid < N_BINS) {
        s_cnt[tid] = 0.0f;
        s_conf[tid] = 0.0f;
        s_corr[tid] = 0.0f;
    }
    __syncthreads();

    const int gtid = blockIdx.x * blockDim.x + tid;
    const int gstride = gridDim.x * blockDim.x;

    for (int row = gtid; row < N; row += gstride) {
        const float4* rp = reinterpret_cast<const float4*>(logits + (size_t)row * C);
        const int lbl = labels[row];  // coalesced across lanes (consecutive rows)

        // 16 independent float4 loads (static indices -> registers, 16-deep MLP)
        float4 q[16];
        #pragma unroll
        for (int j = 0; j < 16; ++j) q[j] = rp[j];

        // max + argmax: 4 independent chains (one per float4 component).
        // Within a chain, strict > keeps the first (lowest-j) occurrence.
        float mx = q[0].x, my = q[0].y, mz = q[0].z, mw = q[0].w;
        int ix = 0, iy = 0, iz = 0, iw = 0;
        #pragma unroll
        for (int j = 1; j < 16; ++j) {
            if (q[j].x > mx) { mx = q[j].x; ix = j; }
            if (q[j].y > my) { my = q[j].y; iy = j; }
            if (q[j].z > mz) { mz = q[j].z; iz = j; }
            if (q[j].w > mw) { mw = q[j].w; iw = j; }
        }
        // merge chains in element-index order (elem = j*4 + comp); on ties the
        // smaller element index wins -> exact jnp.argmax first-index semantics.
        float m = mx; int idx = (ix << 2);
        int cand = (iy << 2) | 1;
        if (my > m || (my == m && cand < idx)) { m = my; idx = cand; }
        cand = (iz << 2) | 2;
        if (mz > m || (mz == m && cand < idx)) { m = mz; idx = cand; }
        cand = (iw << 2) | 3;
        if (mw > m || (mw == m && cand < idx)) { m = mw; idx = cand; }

        // sum of exp(l - max), 4 independent accumulation chains
        float sx = 0.0f, sy = 0.0f, sz = 0.0f, sw = 0.0f;
        #pragma unroll
        for (int j = 0; j < 16; ++j) {
            sx += __expf(q[j].x - m);
            sy += __expf(q[j].y - m);
            sz += __expf(q[j].z - m);
            sw += __expf(q[j].w - m);
        }
        const float conf = 1.0f / ((sx + sy) + (sz + sw));

        int bin = min(max((int)ceilf(conf * (float)N_BINS) - 1, 0), N_BINS - 1);
        atomicAdd(&s_cnt[bin], 1.0f);
        atomicAdd(&s_conf[bin], conf);
        if (idx == lbl) atomicAdd(&s_corr[bin], 1.0f);
    }
    __syncthreads();
    if (tid < N_BINS) {
        // flush block partials into double global accumulators (skip empty bins)
        if (s_cnt[tid] != 0.0f) {
            atomicAdd(&gbins[tid], (double)s_cnt[tid]);
            atomicAdd(&gbins[N_BINS + tid], (double)s_conf[tid]);
            atomicAdd(&gbins[2 * N_BINS + tid], (double)s_corr[tid]);
        }
    }

    // Last-block-does-final: flush visible (threadfence) -> counter -> final.
    if (tid == 0) {
        __threadfence();
        unsigned int old = atomicAdd((unsigned int*)(gbins + WS_COUNTER_OFF), 1u);
        s_last = (old == gridDim.x - 1) ? 1 : 0;
    }
    __syncthreads();
    if (s_last && tid == 0) {
        __threadfence();
        double ece = 0.0;
        for (int b = 0; b < N_BINS; ++b) {
            // atomicAdd(p, 0.0) = coherent read at device scope (cross-XCD safe).
            double cnt = atomicAdd(&gbins[b], 0.0);
            if (cnt > 0.0) {
                double conf = atomicAdd(&gbins[N_BINS + b], 0.0) / cnt;
                double corr = atomicAdd(&gbins[2 * N_BINS + b], 0.0) / cnt;
                double d = conf - corr;
                if (d < 0.0) d = -d;
                ece += d * (cnt / (double)N);
            }
        }
        out[0] = (float)ece;
    }
}

extern "C" void kernel_launch(void* const* d_in, const int* in_sizes, int n_in,
                              void* d_out, int out_size, void* d_ws, size_t ws_size,
                              hipStream_t stream) {
    const float* logits = (const float*)d_in[0];
    const int* labels = (const int*)d_in[1];
    // d_in[2] is `train` (static 1) — the train branch is baked in at trace time.
    float* out = (float*)d_out;
    double* gbins = (double*)d_ws;

    const int N = in_sizes[1];  // 1,000,000 rows

    ece_init_ws<<<1, 64, 0, stream>>>(gbins);
    // 2048 blocks x 256 threads = 524,288 threads, ~2 rows/thread grid-stride.
    ece_main<<<2048, 256, 0, stream>>>(logits, labels, gbins, out, N);
}

// Round 10
// 372.847 us; speedup vs baseline: 1.2105x; 1.2105x over previous
//
#include <hip/hip_runtime.h>
#include <hip/hip_bf16.h>

// ECE loss, train path:
//   conf[r]  = max(softmax(logits[r,:])) = 1 / sum(exp(l - max))
//   pred[r]  = argmax(logits[r,:])   (first index on ties, matches jnp.argmax)
//   bin      = clip(ceil(conf*10)-1, 0, 9)
//   ece      = sum_b |conf_sum/cnt - corr_sum/cnt| * cnt/N
//
// History:
//  R6 (16-lane group + shfl butterflies): 177.8 us. DS-pipe bound: ~12
//     ds_bpermute RTs per 4 rows x ~30cy = ~420K cy/CU — matches exactly.
//  R7 (thread-per-row, global reads):     204.7 us. Uncoalesced: each wave
//     load instr touches 64 distinct lines; vmcnt-latency bound (VALU 6.7%).
// This round: coalesced loads AND zero shuffles. Per-wave LDS transpose:
// stage 64 rows x 256B coalesced -> XOR-swizzled LDS (chunk ^= row&15,
// conflict-free read) -> lane i reduces row i in-register (R7's verified
// reduce). No barriers (per-wave buffer), one lgkmcnt fence per tile.

#define N_BINS 10
#define C 64

// ws layout: [0..9] cnt, [10..19] conf_sum, [20..29] corr_sum (doubles), then counter.
#define WS_COUNTER_OFF 30  // in doubles

__global__ void ece_init_ws(double* ws) {
    int t = threadIdx.x;
    if (t < 3 * N_BINS) ws[t] = 0.0;
    if (t == 0) *(unsigned int*)(ws + WS_COUNTER_OFF) = 0u;
}

// In-register row reduce on 16 float4 chunks (chunk j = elements 4j..4j+3).
// Verified bit-exact in R7 (absmax 0.0). First-index tie-break == jnp.argmax.
__device__ __forceinline__ void reduce_row(const float4* q, float& conf, int& idx) {
    float mx = q[0].x, my = q[0].y, mz = q[0].z, mw = q[0].w;
    int ix = 0, iy = 0, iz = 0, iw = 0;
    #pragma unroll
    for (int j = 1; j < 16; ++j) {
        if (q[j].x > mx) { mx = q[j].x; ix = j; }
        if (q[j].y > my) { my = q[j].y; iy = j; }
        if (q[j].z > mz) { mz = q[j].z; iz = j; }
        if (q[j].w > mw) { mw = q[j].w; iw = j; }
    }
    float m = mx; idx = (ix << 2);
    int cand = (iy << 2) | 1;
    if (my > m || (my == m && cand < idx)) { m = my; idx = cand; }
    cand = (iz << 2) | 2;
    if (mz > m || (mz == m && cand < idx)) { m = mz; idx = cand; }
    cand = (iw << 2) | 3;
    if (mw > m || (mw == m && cand < idx)) { m = mw; idx = cand; }

    float sx = 0.0f, sy = 0.0f, sz = 0.0f, sw = 0.0f;
    #pragma unroll
    for (int j = 0; j < 16; ++j) {
        sx += __expf(q[j].x - m);
        sy += __expf(q[j].y - m);
        sz += __expf(q[j].z - m);
        sw += __expf(q[j].w - m);
    }
    conf = 1.0f / ((sx + sy) + (sz + sw));
}

__global__ __launch_bounds__(256) void ece_main(const float* __restrict__ logits,
                                                const int* __restrict__ labels,
                                                double* __restrict__ gbins,
                                                float* __restrict__ out,
                                                int N) {
    // 16 KB tile per wave (64 rows x 256 B), 4 waves/block = 64 KB -> 2 blocks/CU.
    __shared__ float s_tile[4][4096];
    __shared__ float s_cnt[N_BINS];
    __shared__ float s_conf[N_BINS];
    __shared__ float s_corr[N_BINS];
    __shared__ int s_last;
    const int tid = threadIdx.x;
    if (tid < N_BINS) {
        s_cnt[tid] = 0.0f;
        s_conf[tid] = 0.0f;
        s_corr[tid] = 0.0f;
    }
    __syncthreads();

    const int lane = tid & 63;
    const int wid = tid >> 6;
    const int gw = blockIdx.x * 4 + wid;   // global wave id
    const int nw = gridDim.x * 4;
    const int ntiles = N >> 6;             // 64 rows per tile

    char* tb = (char*)&s_tile[wid][0];

    for (int t = gw; t < ntiles; t += nw) {
        const char* src = (const char*)logits + (size_t)t * 16384;

        // Stage: 16 coalesced float4 loads (instr k covers 1 KB contiguous).
        float4 q[16];
        #pragma unroll
        for (int k = 0; k < 16; ++k)
            q[k] = *(const float4*)(src + k * 1024 + lane * 16);

        // Swizzled LDS write: byte o -> o ^ ((row&15)<<4). Involution on chunk
        // bits [4:7]; row bits [8:13] untouched. Spreads a column read across
        // all 16 bank-quads -> conflict-free ds_read_b128.
        #pragma unroll
        for (int k = 0; k < 16; ++k) {
            const int o = k * 1024 + lane * 16;
            const int dst = o ^ (((o >> 8) & 15) << 4);
            *(float4*)(tb + dst) = q[k];
        }
        // Same-wave write->read fence: all 16 ds_writes complete before reads.
        asm volatile("s_waitcnt lgkmcnt(0)" ::: "memory");

        // Lane = row: gather the 16 chunks of row `lane` (swizzle-adjusted).
        float4 r[16];
        const int rbase = lane << 8;           // row * 256 B
        const int rx = (lane & 15) << 4;       // swizzle key
        #pragma unroll
        for (int j = 0; j < 16; ++j)
            r[j] = *(const float4*)(tb + (rbase + ((j << 4) ^ rx)));

        float conf; int idx;
        reduce_row(r, conf, idx);

        const int lbl = labels[t * 64 + lane];  // coalesced
        int bin = min(max((int)ceilf(conf * (float)N_BINS) - 1, 0), N_BINS - 1);
        atomicAdd(&s_cnt[bin], 1.0f);
        atomicAdd(&s_conf[bin], conf);
        if (idx == lbl) atomicAdd(&s_corr[bin], 1.0f);
    }

    // Tail rows (N % 64) — dormant for N=1M, handled by global wave 0.
    if (gw == 0) {
        const int rem = N & 63;
        if (lane < rem) {
            const int row = (N & ~63) + lane;
            const float4* rp = (const float4*)(logits + (size_t)row * C);
            float4 r[16];
            #pragma unroll
            for (int j = 0; j < 16; ++j) r[j] = rp[j];
            float conf; int idx;
            reduce_row(r, conf, idx);
            int bin = min(max((int)ceilf(conf * (float)N_BINS) - 1, 0), N_BINS - 1);
            atomicAdd(&s_cnt[bin], 1.0f);
            atomicAdd(&s_conf[bin], conf);
            if (idx == labels[row]) atomicAdd(&s_corr[bin], 1.0f);
        }
    }

    __syncthreads();
    if (tid < N_BINS) {
        if (s_cnt[tid] != 0.0f) {
            atomicAdd(&gbins[tid], (double)s_cnt[tid]);
            atomicAdd(&gbins[N_BINS + tid], (double)s_conf[tid]);
            atomicAdd(&gbins[2 * N_BINS + tid], (double)s_corr[tid]);
        }
    }

    // Last-block-does-final: flush visible (threadfence) -> counter -> final.
    if (tid == 0) {
        __threadfence();
        unsigned int old = atomicAdd((unsigned int*)(gbins + WS_COUNTER_OFF), 1u);
        s_last = (old == gridDim.x - 1) ? 1 : 0;
    }
    __syncthreads();
    if (s_last && tid == 0) {
        __threadfence();
        double ece = 0.0;
        for (int b = 0; b < N_BINS; ++b) {
            // atomicAdd(p, 0.0) = coherent read at device scope (cross-XCD safe).
            double cnt = atomicAdd(&gbins[b], 0.0);
            if (cnt > 0.0) {
                double conf = atomicAdd(&gbins[N_BINS + b], 0.0) / cnt;
                double corr = atomicAdd(&gbins[2 * N_BINS + b], 0.0) / cnt;
                double d = conf - corr;
                if (d < 0.0) d = -d;
                ece += d * (cnt / (double)N);
            }
        }
        out[0] = (float)ece;
    }
}

extern "C" void kernel_launch(void* const* d_in, const int* in_sizes, int n_in,
                              void* d_out, int out_size, void* d_ws, size_t ws_size,
                              hipStream_t stream) {
    const float* logits = (const float*)d_in[0];
    const int* labels = (const int*)d_in[1];
    // d_in[2] is `train` (static 1) — the train branch is baked in at trace time.
    float* out = (float*)d_out;
    double* gbins = (double*)d_ws;

    const int N = in_sizes[1];  // 1,000,000 rows

    ece_init_ws<<<1, 64, 0, stream>>>(gbins);
    // 512 blocks x 256 thr: 64KB LDS/block -> 2 blocks/CU, 2048 waves,
    // ~7.6 tiles/wave grid-stride. No intra-loop barriers (per-wave buffers).
    ece_main<<<512, 256, 0, stream>>>(logits, labels, gbins, out, N);
}